// Round 1
// baseline (3069.739 us; speedup 1.0000x reference)
//
#include <hip/hip_runtime.h>
#include <hip/hip_bf16.h>

typedef __attribute__((ext_vector_type(8))) short bf16x8;
typedef __attribute__((ext_vector_type(4))) float f32x4;
typedef unsigned short u16;

__device__ __forceinline__ u16 f2bf(float f) {
  union { float f; unsigned u; } v; v.f = f;
  unsigned r = v.u + 0x7FFFu + ((v.u >> 16) & 1u);   // RTNE
  return (u16)(r >> 16);
}

// ---------------------------------------------------------------------------
// fold: Wt[(j*4+g)][k] = sum_m P[m][j] * (W[k][m] * cos(rx[m]))   (bf16 out)
// GEMM with M-dim=j (512), N-dim=k (1024), K-dim=m (512) so output rows are
// k-contiguous (MFMA B-fragment layout) and gates interleave in n = j*4+g.
// ---------------------------------------------------------------------------
__global__ __launch_bounds__(256) void fold_kernel(
    const float* __restrict__ W, const float* __restrict__ rx,
    const float* __restrict__ P, u16* __restrict__ Wt, int g)
{
  __shared__ __align__(16) float As[16][68];   // As[m][j]
  __shared__ __align__(16) float Bs[16][68];   // Bs[m][k]
  const int bk = blockIdx.x;   // k-tile 0..15
  const int bj = blockIdx.y;   // j-tile 0..7
  const int tid = threadIdx.x;
  const int tx = tid & 15;     // k-dir
  const int ty = tid >> 4;     // j-dir
  const int j0 = bj * 64, k0 = bk * 64;
  float acc[4][4] = {};
  for (int m0 = 0; m0 < 512; m0 += 16) {
#pragma unroll
    for (int l = 0; l < 4; ++l) {
      int lin = tid + 256 * l;                 // 0..1023
      int mm = lin >> 6, jr = lin & 63;
      As[mm][jr] = P[(m0 + mm) * 512 + j0 + jr];
      int kk = lin >> 4, mb = lin & 15;
      Bs[mb][kk] = W[(k0 + kk) * 512 + m0 + mb] * cosf(rx[m0 + mb]);
    }
    __syncthreads();
#pragma unroll
    for (int mm = 0; mm < 16; ++mm) {
      f32x4 a = *(const f32x4*)&As[mm][ty * 4];
      f32x4 b = *(const f32x4*)&Bs[mm][tx * 4];
#pragma unroll
      for (int i = 0; i < 4; ++i)
#pragma unroll
        for (int jj = 0; jj < 4; ++jj)
          acc[i][jj] += a[i] * b[jj];
    }
    __syncthreads();
  }
#pragma unroll
  for (int i = 0; i < 4; ++i) {
    int j = j0 + ty * 4 + i;
    size_t n = (size_t)(j * 4 + g);
    ushort4 w;
    w.x = f2bf(acc[i][0]); w.y = f2bf(acc[i][1]);
    w.z = f2bf(acc[i][2]); w.w = f2bf(acc[i][3]);
    *(ushort4*)(Wt + n * 1024 + k0 + tx * 4) = w;
  }
}

// bpn[j*4+g] = sum_m b[m]*cos(rx[m])*P[m][j]   (f32, tiny)
__global__ __launch_bounds__(256) void fold_bias(
    const float* __restrict__ b, const float* __restrict__ rx,
    const float* __restrict__ P, float* __restrict__ bpn, int g)
{
  int j = blockIdx.x * 256 + threadIdx.x;      // 0..511
  float acc = 0.f;
  for (int m = 0; m < 512; ++m) acc += b[m] * cosf(rx[m]) * P[m * 512 + j];
  bpn[j * 4 + g] = acc;
}

// convert whole input X (T*B*D f32) to bf16 once
__global__ __launch_bounds__(256) void xcvt_kernel(
    const float* __restrict__ x, u16* __restrict__ xb)
{
  size_t i = (size_t)blockIdx.x * 256 + threadIdx.x;  // group of 4 elems
  f32x4 v = *(const f32x4*)(x + i * 4);
  ushort4 w;
  w.x = f2bf(v[0]); w.y = f2bf(v[1]); w.z = f2bf(v[2]); w.w = f2bf(v[3]);
  *(ushort4*)(xb + i * 4) = w;
}

__global__ __launch_bounds__(256) void init_kernel(u16* h0, float* c) {
  int i = blockIdx.x * 256 + threadIdx.x;      // 65536
  h0[i] = 0; c[i] = 0.f;
}

__global__ __launch_bounds__(256) void tail_kernel(
    const float* __restrict__ hlast, const float* __restrict__ c,
    float* __restrict__ hx, float* __restrict__ cx)
{
  int i = blockIdx.x * 256 + threadIdx.x;      // 65536
  hx[i] = hlast[i];
  cx[i] = c[i];
}

// ---------------------------------------------------------------------------
// one recurrence step: pre = [x_t|h] @ Wbig + b ; gates ; cell update
// grid 256 = 4 b-blocks(32) x 64 n-tiles(32 cols = 8 j x 4 gates)
// bid = mb*64+nb  ->  bid%8 == nb%8 : same-nb wgs pinned to one XCD (W reuse)
// ---------------------------------------------------------------------------
__global__ __launch_bounds__(256) void step_kernel(
    const u16* __restrict__ xb_t,   // [128][512] bf16 (pre-converted x_t)
    const u16* __restrict__ h_in,   // [128][512] bf16
    u16* __restrict__ h_out,        // [128][512] bf16
    const u16* __restrict__ Wt,     // [2048][1024] bf16, n = j*4+g
    const float* __restrict__ bpn,  // [2048] f32
    float* __restrict__ cbuf,       // [128][512] f32 (in/out)
    float* __restrict__ out_t)      // d_out + t*65536  (f32)
{
  __shared__ float pre_s[32][33];
  const int bid = blockIdx.x;
  const int mb = bid >> 6;           // 0..3
  const int nb = bid & 63;           // 0..63
  const int b0 = mb * 32;
  const int n0 = nb * 32;
  const int tid = threadIdx.x;
  const int wv = tid >> 6;
  const int lane = tid & 63;
  const int rt = wv >> 1;            // row-tile (16 b's)
  const int nt = wv & 1;             // n-tile (16 cols)
  const int l15 = lane & 15;
  const int kg = lane >> 4;          // k-group 0..3
  const int brow = b0 + rt * 16 + l15;
  const int ncol = n0 + nt * 16 + l15;

  const u16*  wrow = Wt + (size_t)ncol * 1024;
  const u16*  xrow = xb_t + (size_t)brow * 512;
  const u16*  hrow = h_in + (size_t)brow * 512;

  f32x4 acc = {0.f, 0.f, 0.f, 0.f};
#pragma unroll 8
  for (int kk = 0; kk < 32; ++kk) {
    const int kb = kk * 32 + kg * 8;           // wave-uniform predicate below
    bf16x8 bfrag = *(const bf16x8*)(wrow + kb);
    bf16x8 afrag;
    if (kb < 512) {
      afrag = *(const bf16x8*)(xrow + kb);
    } else {
      afrag = *(const bf16x8*)(hrow + (kb - 512));
    }
    acc = __builtin_amdgcn_mfma_f32_16x16x32_bf16(afrag, bfrag, acc, 0, 0, 0);
  }

  // C/D layout (m89-verified): col = lane&15, row = (lane>>4)*4 + q
  const float bias = bpn[ncol];
#pragma unroll
  for (int q = 0; q < 4; ++q) {
    int row = rt * 16 + kg * 4 + q;            // b-offset within wg
    pre_s[row][nt * 16 + l15] = acc[q] + bias;
  }
  __syncthreads();

  // cell update: 256 threads <-> 32 b x 8 j ; gates g at col jo*4+g
  const int bb = tid >> 3, jo = tid & 7;
  const int b = b0 + bb, j = nb * 8 + jo;
  float pf = pre_s[bb][jo * 4 + 0];
  float pi = pre_s[bb][jo * 4 + 1];
  float pu = pre_s[bb][jo * 4 + 2];
  float po = pre_s[bb][jo * 4 + 3];
  float fg = 1.f / (1.f + __expf(-pf));
  float ig = 1.f / (1.f + __expf(-pi));
  float gg = tanhf(pu);
  float og = 1.f / (1.f + __expf(-po));
  size_t idx = (size_t)b * 512 + j;
  float cv = fg * cbuf[idx] + ig * gg;
  cbuf[idx] = cv;
  float hv = og * tanhf(cv);
  out_t[idx] = hv;
  h_out[idx] = f2bf(hv);
}

// ---------------------------------------------------------------------------
extern "C" void kernel_launch(void* const* d_in, const int* in_sizes, int n_in,
                              void* d_out, int out_size, void* d_ws, size_t ws_size,
                              hipStream_t stream) {
  (void)in_sizes; (void)n_in; (void)out_size; (void)ws_size;
  const float* inp = (const float*)d_in[0];
  float* out = (float*)d_out;

  // ws layout (all 16B aligned):
  //   Xbf  : 256*128*512 u16 = 33,554,432 B
  //   Wt   : 2048*1024  u16  =  4,194,304 B
  //   bpn  : 2048 f32        =      8,192 B
  //   hbf  : 2*128*512 u16   =    262,144 B
  //   cbuf : 128*512 f32     =    262,144 B
  u16*   Xbf  = (u16*)d_ws;
  u16*   Wt   = (u16*)((char*)d_ws + 33554432);
  float* bpn  = (float*)((char*)d_ws + 33554432 + 4194304);
  u16*   hbf  = (u16*)((char*)d_ws + 33554432 + 4194304 + 8192);
  float* cbuf = (float*)((char*)d_ws + 33554432 + 4194304 + 8192 + 262144);

  // input order (setup_inputs dict): inputs, then per gate g: W, b, rx, P
  for (int g = 0; g < 4; ++g) {
    const float* W  = (const float*)d_in[1 + 4 * g];
    const float* b  = (const float*)d_in[2 + 4 * g];
    const float* rx = (const float*)d_in[3 + 4 * g];
    const float* P  = (const float*)d_in[4 + 4 * g];
    fold_kernel<<<dim3(16, 8), 256, 0, stream>>>(W, rx, P, Wt, g);
    fold_bias<<<dim3(2), 256, 0, stream>>>(b, rx, P, bpn, g);
  }
  xcvt_kernel<<<16384, 256, 0, stream>>>(inp, Xbf);   // 16.7M elems / 4 per thr
  init_kernel<<<256, 256, 0, stream>>>(hbf, cbuf);

  for (int t = 0; t < 256; ++t) {
    const u16* xb_t  = Xbf + (size_t)t * 65536;
    const u16* h_in  = hbf + (size_t)(t & 1) * 65536;
    u16*       h_oup = hbf + (size_t)((t & 1) ^ 1) * 65536;
    float*     out_t = out + (size_t)t * 65536;
    step_kernel<<<256, 256, 0, stream>>>(xb_t, h_in, h_oup, Wt, bpn, cbuf, out_t);
  }

  tail_kernel<<<256, 256, 0, stream>>>(out + (size_t)255 * 65536, cbuf,
                                       out + (size_t)256 * 65536,
                                       out + (size_t)256 * 65536 + 65536);
}